// Round 3
// baseline (2047.305 us; speedup 1.0000x reference)
//
#include <hip/hip_runtime.h>
#include <cstdint>

#define HID 4096
#define SEQ 1024
#define B_REQ 4
#define NH 32
#define DH 128
#define RANK 16

typedef unsigned short u16;
typedef __attribute__((ext_vector_type(8))) short short8;
typedef __attribute__((ext_vector_type(8))) unsigned short us8;
typedef __attribute__((ext_vector_type(4))) float f32x4;

static __device__ __forceinline__ float bf2f(u16 u) {
  union { unsigned int i; float f; } v; v.i = ((unsigned int)u) << 16; return v.f;
}
static __device__ __forceinline__ u16 f2bf(float f) {
  union { float f; unsigned int i; } v; v.f = f;
  unsigned int r = v.i + 0x7FFFu + ((v.i >> 16) & 1u);  // RNE
  return (u16)(r >> 16);
}

template<typename T> struct io;
template<> struct io<u16> {
  static __device__ __forceinline__ float ld(const u16* p, size_t i) { return bf2f(p[i]); }
  static __device__ __forceinline__ void st(u16* p, size_t i, float v) { p[i] = f2bf(v); }
};
template<> struct io<float> {
  static __device__ __forceinline__ float ld(const float* p, size_t i) { return p[i]; }
  static __device__ __forceinline__ void st(float* p, size_t i, float v) { p[i] = v; }
};

// ---------- dtype probe: bf16 weights never have exponent >= 0xC0; fp32 low halves do ----------
__global__ void detect_k(const u16* __restrict__ w, int* __restrict__ dflag) {
  if (threadIdx.x == 0 && blockIdx.x == 0) {
    int huge = 0;
    for (int i = 0; i < 2048; i++) {
      int e = (w[i] >> 7) & 0xFF;
      if (e >= 0xC0) huge++;
    }
    dflag[0] = (huge > 8) ? 1 : 0;   // 1 => inputs are float32
  }
}

// ---------- convert input matrix to bf16 (identity when already bf16) ----------
template<typename T>
__global__ __launch_bounds__(256) void convert_k(const int* __restrict__ fl, int want,
    const T* __restrict__ src, u16* __restrict__ dst, int n) {
  if (fl[0] != want) return;
  int stride = gridDim.x * blockDim.x;
  for (int i = blockIdx.x * blockDim.x + threadIdx.x; i < n; i += stride)
    dst[i] = f2bf(io<T>::ld(src, i));
}

// ---------- transpose 4096x4096: T[n][k] = bf16(W[k][n]) ----------
template<typename T>
__global__ __launch_bounds__(256) void transpose_k(const int* __restrict__ fl, int want,
    const T* __restrict__ W, u16* __restrict__ Tt) {
  if (fl[0] != want) return;
  __shared__ u16 st[64][68];
  int r0 = blockIdx.y * 64, c0 = blockIdx.x * 64;
  int t = threadIdx.x;
  int r = t >> 2, cb = (t & 3) * 16;
#pragma unroll
  for (int j = 0; j < 16; j++)
    st[r][cb + j] = f2bf(io<T>::ld(W, (size_t)(r0 + r) * HID + c0 + cb + j));
  __syncthreads();
#pragma unroll
  for (int j = 0; j < 4; j++) {
    int cw = cb + j*4;
    ushort4 v;
    v.x = st[cw+0][r]; v.y = st[cw+1][r]; v.z = st[cw+2][r]; v.w = st[cw+3][r];
    *(ushort4*)&Tt[(size_t)(c0 + r) * HID + r0 + cw] = v;
  }
}

// ---------- r[b,s,:] = x_row @ A_b  (K=4096, R=16). z selects A matrix. ----------
template<typename T>
__global__ __launch_bounds__(256) void lora_r_k(const int* __restrict__ fl, int want,
    const u16* __restrict__ X, const T* __restrict__ A0,
    const T* __restrict__ A1, const T* __restrict__ A2, float* __restrict__ R) {
  if (fl[0] != want) return;
  int s = blockIdx.x, b = blockIdx.y, m = blockIdx.z;
  const T* A = (m==0?A0: m==1?A1:A2) + (size_t)b * HID * RANK;
  const u16* x = X + (size_t)(b*SEQ + s) * HID;
  float* r = R + ((size_t)(m*B_REQ + b) * SEQ + s) * RANK;
  int t = threadIdx.x;
  int c = t >> 4;                       // d = c + 16*i  -> A idx = t + 256*i (coalesced)
  float acc = 0.f;
  for (int i = 0; i < 256; i++)
    acc += bf2f(x[c + 16*i]) * io<T>::ld(A, t + 256*i);
  __shared__ float red[256];
  red[t] = acc;
  __syncthreads();
  if (t < 16) {
    float sum = 0.f;
#pragma unroll
    for (int cc = 0; cc < 16; cc++) sum += red[cc*16 + t];
    r[t] = sum;
  }
}

// ---------- C(4096x4096) = A @ BT^T, A/BT bf16, C dtype TOUT. m97 structure. ----------
template<typename TOUT>
__global__ __launch_bounds__(256) void gemm_bt_k(const int* __restrict__ fl, int want,
    const u16* __restrict__ A, const u16* __restrict__ BT, TOUT* __restrict__ C) {
  if (want >= 0 && fl[0] != want) return;
  __shared__ u16 sA[128*32];
  __shared__ u16 sB[128*32];
  int tid = threadIdx.x, lane = tid & 63, wave = tid >> 6;
  int l15 = lane & 15, quad = lane >> 4;
  int wm = wave >> 1, wn = wave & 1;
  int m0 = blockIdx.x * 128, n0 = blockIdx.y * 128;
  f32x4 acc[4][4];
  f32x4 zero = {0.f,0.f,0.f,0.f};
#pragma unroll
  for (int i=0;i<4;i++)
#pragma unroll
    for (int j=0;j<4;j++) acc[i][j] = zero;
  const u16* gA = A  + (size_t)(m0 + wave*32 + (lane>>2)) * HID + (lane&3)*8;
  const u16* gB = BT + (size_t)(n0 + wave*32 + (lane>>2)) * HID + (lane&3)*8;
  u16* lA = sA + (wave*32)*32;
  u16* lB = sB + (wave*32)*32;
  for (int k0 = 0; k0 < HID; k0 += 32) {
    __syncthreads();
#pragma unroll
    for (int i = 0; i < 2; i++) {
      __builtin_amdgcn_global_load_lds(
          (const __attribute__((address_space(1))) void*)(gA + (size_t)i*16*HID + k0),
          (__attribute__((address_space(3))) void*)(lA + i*16*32), 16, 0, 0);
      __builtin_amdgcn_global_load_lds(
          (const __attribute__((address_space(1))) void*)(gB + (size_t)i*16*HID + k0),
          (__attribute__((address_space(3))) void*)(lB + i*16*32), 16, 0, 0);
    }
    __syncthreads();
    short8 af[4], bfr[4];
#pragma unroll
    for (int tm=0;tm<4;tm++) af[tm]  = *(const short8*)&sA[(wm*64 + tm*16 + l15)*32 + quad*8];
#pragma unroll
    for (int tn=0;tn<4;tn++) bfr[tn] = *(const short8*)&sB[(wn*64 + tn*16 + l15)*32 + quad*8];
#pragma unroll
    for (int tm=0;tm<4;tm++)
#pragma unroll
      for (int tn=0;tn<4;tn++)
        acc[tm][tn] = __builtin_amdgcn_mfma_f32_16x16x32_bf16(af[tm], bfr[tn], acc[tm][tn], 0, 0, 0);
  }
  int rb = m0 + wm*64 + quad*4;
  int cb = n0 + wn*64 + l15;
#pragma unroll
  for (int tm=0;tm<4;tm++)
#pragma unroll
    for (int tn=0;tn<4;tn++)
#pragma unroll
      for (int rr=0;rr<4;rr++)
        io<TOUT>::st(C, (size_t)(rb + tm*16 + rr) * HID + cb + tn*16, acc[tm][tn][rr]);
}

// ---------- in-place bf16: val = lin + r@B ; rope for kind 0,1 ; plain for kind 2 ----------
template<typename T>
__global__ __launch_bounds__(128) void lora_rope_k(const int* __restrict__ fl, int want,
    u16* __restrict__ Qb, u16* __restrict__ Kb, u16* __restrict__ Vb,
    const float* __restrict__ R,
    const T* __restrict__ Bq, const T* __restrict__ Bk, const T* __restrict__ Bv) {
  if (fl[0] != want) return;
  int s = blockIdx.x, h = blockIdx.y, z = blockIdx.z;
  int kind = z >> 2, b = z & 3;
  u16* Ob = kind==0?Qb: kind==1?Kb:Vb;
  const T* Bm = (kind==0?Bq: kind==1?Bk:Bv) + (size_t)b * RANK * HID;
  const float* r = R + ((size_t)(kind*B_REQ + b) * SEQ + s) * RANK;
  int d = threadIdx.x;
  __shared__ float rr[RANK];
  __shared__ float vbuf[DH];
  if (d < RANK) rr[d] = r[d];
  __syncthreads();
  size_t idx = (size_t)(b*SEQ + s) * HID + h*DH + d;
  float val = bf2f(Ob[idx]);
  int col = h*DH + d;
#pragma unroll
  for (int j = 0; j < RANK; j++) val += rr[j] * io<T>::ld(Bm, (size_t)j*HID + col);
  if (kind == 2) { Ob[idx] = f2bf(val); return; }
  vbuf[d] = val;
  __syncthreads();
  int dd = d & 63;
  // inv_freq = 10000^(-dd/64) = 2^(-dd*log2(10000)/64)
  float ang = (float)s * exp2f((float)dd * (-13.287712379549449f / 64.f));
  float sn, cs;
  sincosf(ang, &sn, &cs);
  float other = (d < 64) ? vbuf[d + 64] : vbuf[d - 64];
  float o = (d < 64) ? (val * cs - other * sn) : (val * cs + other * sn);
  Ob[idx] = f2bf(o);
}

// ---------- flash attention: block = (b, h, 64 q rows), 4 waves x 16 q rows ----------
__global__ __launch_bounds__(256) void attn_k(
    const u16* __restrict__ Q, const u16* __restrict__ K, const u16* __restrict__ V,
    u16* __restrict__ O) {
  int qb = blockIdx.x, h = blockIdx.y, b = blockIdx.z;
  int q0 = qb * 64;
  int tid = threadIdx.x, lane = tid & 63, wave = tid >> 6;
  int l15 = lane & 15, quad = lane >> 4;
  __shared__ u16 sK[32*136];       // [krow][d], stride 136 elems (272B, 16B-aligned)
  __shared__ u16 sVT[128*40];      // [d][krow], stride 40 elems (80B, 16B-aligned)
  __shared__ u16 sP[4][16*40];     // wave-private P [q][k], stride 40
  short8 qf[4];
  {
    const u16* qp = Q + (size_t)(b*SEQ + q0 + wave*16 + l15) * HID + h*DH + quad*8;
#pragma unroll
    for (int c = 0; c < 4; c++) qf[c] = *(const short8*)(qp + c*32);
  }
  f32x4 zero = {0.f,0.f,0.f,0.f};
  f32x4 oacc[8];
#pragma unroll
  for (int i=0;i<8;i++) oacc[i] = zero;
  float m_i[4], l_i[4];
#pragma unroll
  for (int r=0;r<4;r++){ m_i[r] = -1e30f; l_i[r] = 0.f; }
  int sr = tid >> 3;               // staging row 0..31
  int sc = (tid & 7) * 16;         // staging col 0..112
  const u16* kb = K + (size_t)(b*SEQ) * HID + h*DH;
  const u16* vb = V + (size_t)(b*SEQ) * HID + h*DH;
  int nkt = (q0 + 64) / 32;
  for (int kt = 0; kt < nkt; kt++) {
    int k0 = kt * 32;
    __syncthreads();
    {
      const u16* kg = kb + (size_t)(k0 + sr) * HID + sc;
      us8 kv0 = *(const us8*)kg;
      us8 kv1 = *(const us8*)(kg + 8);
      *(us8*)&sK[sr*136 + sc]     = kv0;
      *(us8*)&sK[sr*136 + sc + 8] = kv1;
      const u16* vg = vb + (size_t)(k0 + sr) * HID + sc;
      us8 v0v = *(const us8*)vg;
      us8 v1v = *(const us8*)(vg + 8);
#pragma unroll
      for (int j=0;j<8;j++) sVT[(sc+j)*40 + sr]   = ((const u16*)&v0v)[j];
#pragma unroll
      for (int j=0;j<8;j++) sVT[(sc+8+j)*40 + sr] = ((const u16*)&v1v)[j];
    }
    __syncthreads();
    int q_hi = q0 + wave*16 + 15;
    if (k0 <= q_hi) {              // wave-uniform skip of fully-masked tiles
      f32x4 s0 = zero, s1 = zero;
#pragma unroll
      for (int c = 0; c < 4; c++) {
        short8 kf0 = *(const short8*)&sK[(l15)*136      + c*32 + quad*8];
        short8 kf1 = *(const short8*)&sK[(16 + l15)*136 + c*32 + quad*8];
        s0 = __builtin_amdgcn_mfma_f32_16x16x32_bf16(qf[c], kf0, s0, 0,0,0);
        s1 = __builtin_amdgcn_mfma_f32_16x16x32_bf16(qf[c], kf1, s1, 0,0,0);
      }
      const float scale = 0.08838834764831845f;   // 1/sqrt(128)
      float alpha[4], p0v[4], p1v[4];
#pragma unroll
      for (int r = 0; r < 4; r++) {
        int q_abs = q0 + wave*16 + quad*4 + r;
        float v0 = s0[r] * scale;
        float v1 = s1[r] * scale;
        if (k0 + l15 > q_abs)      v0 = -1e30f;
        if (k0 + 16 + l15 > q_abs) v1 = -1e30f;
        float mx = fmaxf(v0, v1);
#pragma unroll
        for (int sh = 1; sh < 16; sh <<= 1) mx = fmaxf(mx, __shfl_xor(mx, sh, 64));
        float mnew = fmaxf(m_i[r], mx);
        float a  = __expf(m_i[r] - mnew);
        float p0 = __expf(v0 - mnew);
        float p1 = __expf(v1 - mnew);
        float rs = p0 + p1;
#pragma unroll
        for (int sh = 1; sh < 16; sh <<= 1) rs += __shfl_xor(rs, sh, 64);
        l_i[r] = a * l_i[r] + rs;
        m_i[r] = mnew;
        alpha[r] = a;
        p0v[r] = p0; p1v[r] = p1;
      }
#pragma unroll
      for (int dt=0; dt<8; dt++)
#pragma unroll
        for (int r=0;r<4;r++) oacc[dt][r] *= alpha[r];
#pragma unroll
      for (int r=0;r<4;r++) {
        sP[wave][(quad*4+r)*40 + l15]      = f2bf(p0v[r]);
        sP[wave][(quad*4+r)*40 + 16 + l15] = f2bf(p1v[r]);
      }
      // within-wave cross-lane LDS dependency: fence so the reads below see the writes
      asm volatile("s_waitcnt lgkmcnt(0)" ::: "memory");
      short8 pf = *(const short8*)&sP[wave][l15*40 + quad*8];  // C-layout -> A-layout via LDS
#pragma unroll
      for (int dt = 0; dt < 8; dt++) {
        short8 vf = *(const short8*)&sVT[(dt*16 + l15)*40 + quad*8];
        oacc[dt] = __builtin_amdgcn_mfma_f32_16x16x32_bf16(pf, vf, oacc[dt], 0,0,0);
      }
    }
  }
  u16* op = O + (size_t)(b*SEQ + q0 + wave*16 + quad*4) * HID + h*DH + l15;
#pragma unroll
  for (int dt=0; dt<8; dt++)
#pragma unroll
    for (int r=0;r<4;r++) {
      float v = oacc[dt][r] / l_i[r];
      op[(size_t)r * HID + dt*16] = f2bf(v);
    }
}

// ---------- in-place: Out += r_o @ Bo ----------
template<typename T>
__global__ __launch_bounds__(256) void out_add_k(const int* __restrict__ fl, int want,
    const float* __restrict__ Ro, const T* __restrict__ Bo, T* __restrict__ Out) {
  if (fl[0] != want) return;
  int c = blockIdx.x * 256 + threadIdx.x;
  int s = blockIdx.y, b = blockIdx.z;
  __shared__ float rr[RANK];
  if (threadIdx.x < RANK) rr[threadIdx.x] = Ro[((size_t)(b*SEQ + s)) * RANK + threadIdx.x];
  __syncthreads();
  size_t row = (size_t)(b*SEQ + s);
  float val = io<T>::ld(Out, row*HID + c);
  const T* bo = Bo + (size_t)b * RANK * HID;
#pragma unroll
  for (int j = 0; j < RANK; j++) val += rr[j] * io<T>::ld(bo, (size_t)j*HID + c);
  io<T>::st(Out, row*HID + c, val);
}

extern "C" void kernel_launch(void* const* d_in, const int* in_sizes, int n_in,
                              void* d_out, int out_size, void* d_ws, size_t ws_size,
                              hipStream_t stream) {
  char* ws = (char*)d_ws;
  const size_t MAT = (size_t)4096 * 4096 * 2;   // one bf16 4096^2 matrix (32 MB)
  // ws layout — peak ~130.1 MB:
  u16* slot0 = (u16*)(ws + 0*MAT);              // W^T staging, then attention output
  u16* slot1 = (u16*)(ws + 1*MAT);              // k_lin, then Wo^T
  u16* slot2 = (u16*)(ws + 2*MAT);              // v_lin
  u16* X_bf  = (u16*)(ws + 3*MAT);              // bf16 copy of hidden_states
  float* r_all = (float*)(ws + 4*MAT);
  float* r_o   = (float*)(ws + 4*MAT + (size_t)3*B_REQ*SEQ*RANK*sizeof(float));
  int* dflag   = (int*)(ws + 4*MAT + (size_t)4*B_REQ*SEQ*RANK*sizeof(float));

  u16* q_lin = (u16*)d_out;   // scratch until the O-proj GEMM rewrites d_out
  u16* k_lin = slot1;
  u16* v_lin = slot2;
  u16* attnb = slot0;

  const int NX = B_REQ * SEQ * HID;             // 16.7M elements

  detect_k<<<1, 64, 0, stream>>>((const u16*)d_in[1], dflag);

#define BOTH(call_b, call_f) do { call_b; call_f; } while (0)
  BOTH((convert_k<u16>  <<<8192,256,0,stream>>>(dflag,0,(const u16*)  d_in[0], X_bf, NX)),
       (convert_k<float><<<8192,256,0,stream>>>(dflag,1,(const float*)d_in[0], X_bf, NX)));
  BOTH((lora_r_k<u16>  <<<dim3(SEQ,B_REQ,3),256,0,stream>>>(dflag,0,X_bf,(const u16*)d_in[5],(const u16*)d_in[7],(const u16*)d_in[9],r_all)),
       (lora_r_k<float><<<dim3(SEQ,B_REQ,3),256,0,stream>>>(dflag,1,X_bf,(const float*)d_in[5],(const float*)d_in[7],(const float*)d_in[9],r_all)));

  // QKV projections
  u16* lin[3] = { q_lin, k_lin, v_lin };
  for (int m = 0; m < 3; m++) {
    BOTH((transpose_k<u16>  <<<dim3(64,64),256,0,stream>>>(dflag,0,(const u16*)  d_in[1+m], slot0)),
         (transpose_k<float><<<dim3(64,64),256,0,stream>>>(dflag,1,(const float*)d_in[1+m], slot0)));
    gemm_bt_k<u16><<<dim3(32,32),256,0,stream>>>(dflag,-1, X_bf, slot0, lin[m]);
  }
  BOTH((lora_rope_k<u16>  <<<dim3(SEQ,NH,12),128,0,stream>>>(dflag,0,q_lin,k_lin,v_lin,r_all,(const u16*)d_in[6],(const u16*)d_in[8],(const u16*)d_in[10])),
       (lora_rope_k<float><<<dim3(SEQ,NH,12),128,0,stream>>>(dflag,1,q_lin,k_lin,v_lin,r_all,(const float*)d_in[6],(const float*)d_in[8],(const float*)d_in[10])));

  attn_k<<<dim3(16,NH,B_REQ),256,0,stream>>>(q_lin, k_lin, v_lin, attnb);

  BOTH((lora_r_k<u16>  <<<dim3(SEQ,B_REQ,1),256,0,stream>>>(dflag,0,attnb,(const u16*)d_in[11],(const u16*)d_in[11],(const u16*)d_in[11],r_o)),
       (lora_r_k<float><<<dim3(SEQ,B_REQ,1),256,0,stream>>>(dflag,1,attnb,(const float*)d_in[11],(const float*)d_in[11],(const float*)d_in[11],r_o)));
  BOTH((transpose_k<u16>  <<<dim3(64,64),256,0,stream>>>(dflag,0,(const u16*)  d_in[4], slot1)),
       (transpose_k<float><<<dim3(64,64),256,0,stream>>>(dflag,1,(const float*)d_in[4], slot1)));
  BOTH((gemm_bt_k<u16>  <<<dim3(32,32),256,0,stream>>>(dflag,0, attnb, slot1, (u16*)d_out)),
       (gemm_bt_k<float><<<dim3(32,32),256,0,stream>>>(dflag,1, attnb, slot1, (float*)d_out)));
  BOTH((out_add_k<u16>  <<<dim3(16,SEQ,B_REQ),256,0,stream>>>(dflag,0,r_o,(const u16*)d_in[12],(u16*)d_out)),
       (out_add_k<float><<<dim3(16,SEQ,B_REQ),256,0,stream>>>(dflag,1,r_o,(const float*)d_in[12],(float*)d_out)));
#undef BOTH
}